// Round 7
// baseline (496.536 us; speedup 1.0000x reference)
//
#include <hip/hip_runtime.h>
#include <hip/hip_fp16.h>

// ---------------------------------------------------------------------------
// TFN-lite layer, MI355X, round 7. Three graph nodes:
//   memset(cnt+ticket) -> prep_all(LDS fold + table + scatter) -> tfn_node.
//
//  * wa(d) fp16 table T[j][c'], c' = t*64 + (u*8+wo); 8-lane edge-groups read
//    each 128B chunk coalesced (proven R4/R6 layout).
//  * prep_all: per block, fold W2 -> w2f[64][320] fp32 in LDS (80 KB), then
//    8 table rows read from LDS (was: 576 divergent L2 loads per wave in R6).
//  * Bucket CSR: scol[row*CAP + atomicAdd(cnt[row])]; CAP=128 >> Poisson(16).
//  * tfn_node: persistent waves draining an atomic ticket (balances variable
//    node degree); per-round software pipeline prefetches next col+pos;
//    recursive-halving reduce-scatter; lane<32 coalesced 128B store + silu.
// ---------------------------------------------------------------------------

#define INV_S3  0.5773502691896258f   // 1/sqrt(3)
#define A0S     0.1767766952966369f   // 1/sqrt(32)
#define A1S     0.27386127875258306f  // sqrt(3)/sqrt(40)
#define S15     3.872983346207417f    // sqrt(15)
#define S5      2.23606797749979f     // sqrt(5)
#define INV_S10 0.31622776601683794f  // 1/sqrt(10)   (cg121 normalized)
#define INV_S30 0.18257418583505536f  // 1/sqrt(30)

#define TBL   2048
#define DMAX  8.0f
#define CAP   128

typedef _Float16 half8 __attribute__((ext_vector_type(8)));

// ---------------------------------------------------------------------------
// K1: fold W2 into LDS once per block, build 8 table rows from LDS, then
// grid-stride bucket scatter of edges.
__global__ __launch_bounds__(320) void prep_all(
    const float* __restrict__ W1, const float* __restrict__ W2,
    const int* __restrict__ ei, _Float16* __restrict__ T,
    int* __restrict__ cnt, int* __restrict__ scol, int E) {

    __shared__ float w2s[64 * 320];   // 80 KiB folded weights
    __shared__ float hs[64];
    int tid = threadIdx.x;            // 0..319  == table column c'
    int bid = blockIdx.x;

    // ---- fold: w2s[k][c'] = folded W2 column (coalesced-ish, L2-hot) ----
    {
        int t = tid >> 6, r = tid & 63;
        int u = r >> 3, wo = r & 7;
        int src = (t < 4) ? (t * 128 + u * 16 + wo) : (512 + u * 8 + wo);
        bool twin = (t < 4);
        for (int k = 0; k < 64; ++k) {
            float v = W2[k * 576 + src];
            if (twin) v += W2[k * 576 + src + 8];
            w2s[k * 320 + tid] = v;
        }
    }

    // ---- 8 table rows for this block ----
    for (int jj = 0; jj < 8; ++jj) {
        int j = bid * 8 + jj;
        float d = (float)j * (DMAX / (float)(TBL - 1));
        __syncthreads();              // fold/hs-rewrite protection
        if (tid < 64) {
            float acc = 0.f;
#pragma unroll
            for (int i = 0; i < 16; ++i) {
                float t = d - (float)i * (1.0f / 3.0f);
                float r = __expf(-4.5f * t * t);
                acc = fmaf(r, W1[i * 64 + tid], acc);
            }
            hs[tid] = fmaxf(acc, 0.f) * 0.25f;   // /sqrt(16)
        }
        __syncthreads();
        float acc = 0.f;
#pragma unroll 8
        for (int k = 0; k < 64; ++k) acc = fmaf(hs[k], w2s[k * 320 + tid], acc);
        T[(size_t)j * 320 + tid] = (_Float16)acc;
    }

    // ---- bucket scatter (independent of table phase) ----
    int gtid = bid * 320 + tid;
    int gsz = gridDim.x * 320;
    for (int e = gtid; e < E; e += gsz) {
        int row = ei[e];
        int p = atomicAdd(&cnt[row], 1);
        if (p < CAP) scol[(size_t)row * CAP + p] = ei[E + e];
    }
}

// ---------------------------------------------------------------------------
// K2: persistent waves, one node per ticket.
__global__ __launch_bounds__(256) void tfn_node(
    const float* __restrict__ x, const float* __restrict__ pos,
    const int* __restrict__ scol, const int* __restrict__ cnt,
    const _Float16* __restrict__ T, int* __restrict__ ticket,
    float* __restrict__ y, int N) {

    int lane = threadIdx.x & 63;
    int g = lane >> 3;
    int u = lane & 7;

    while (true) {
        int tk;
        if (lane == 0) tk = atomicAdd(ticket, 1);
        tk = __shfl(tk, 0, 64);
        if (tk >= N) break;
        int n = tk;

        int kc = cnt[n];
        if (kc > CAP) kc = CAP;
        const int* nbr = scol + (size_t)n * CAP;

        const float* xr = x + (size_t)n * 32;
        float xu  = xr[u];
        float xv0 = xr[8 + 3 * u + 0];
        float xv1 = xr[8 + 3 * u + 1];
        float xv2 = xr[8 + 3 * u + 2];
        float prx = pos[3 * n + 0], pry = pos[3 * n + 1], prz = pos[3 * n + 2];

        // V: 32 output channels. V[z]=scalar z; vec w comp k -> V[8+3w+k].
        float V[32];
#pragma unroll
        for (int z = 0; z < 32; ++z) V[z] = 0.f;

        int rounds = (kc + 7) >> 3;

        // software pipeline: prefetch round 0's col+pos
        int slot = g;
        bool val = slot < kc;
        float evx = 0.f, evy = 0.f, evz = 0.f;
        if (val) {
            int col = nbr[slot];
            evx = prx - pos[3 * col + 0];
            evy = pry - pos[3 * col + 1];
            evz = prz - pos[3 * col + 2];
        }

        for (int rd = 0; rd < rounds; ++rd) {
            bool cval = val;
            float cex = evx, cey = evy, cez = evz;
            // issue next round's loads before current math
            slot += 8;
            val = slot < kc;
            if (val) {
                int ncol = nbr[slot];
                evx = prx - pos[3 * ncol + 0];
                evy = pry - pos[3 * ncol + 1];
                evz = prz - pos[3 * ncol + 2];
            }
            if (cval) {
                float d2 = cex * cex + cey * cey + cez * cez + 1e-12f;
                float invd = rsqrtf(d2);
                float dd = d2 * invd;
                float nx = cex * invd, ny = cey * invd, nz = cez * invd;

                float fj = dd * ((float)(TBL - 1) / DMAX);
                int j0 = (int)fj;
                j0 = min(j0, TBL - 2);
                float tf = fminf(fj - (float)j0, 1.0f);
                _Float16 th = (_Float16)tf;

                const _Float16* Ar = T + (size_t)j0 * 320 + u * 8;
                half8 A[5], B[5];
#pragma unroll
                for (int t = 0; t < 5; ++t) {
                    A[t] = *(const half8*)(Ar + t * 64);
                    B[t] = *(const half8*)(Ar + 320 + t * 64);
                }

                // geometry while table loads are in flight
                float qu = xv0 * nx + xv1 * ny + xv2 * nz;   // (xv[u].Y1)/S3
                float Y22 = 0.5f * S5 * (3.f * ny * ny - 1.f);
                float Y24 = 0.5f * S15 * (nz * nz - nx * nx);
                float M00 = -Y22 * INV_S30 - Y24 * INV_S10;
                float M11 = 2.f * Y22 * INV_S30;
                float M22 = -Y22 * INV_S30 + Y24 * INV_S10;
                float M01 = (S15 * nx * ny) * INV_S10;
                float M02 = (S15 * nx * nz) * INV_S10;
                float M12 = (S15 * ny * nz) * INV_S10;
                float m0 = M00 * xv0 + M01 * xv1 + M02 * xv2;
                float m1 = M01 * xv0 + M11 * xv1 + M12 * xv2;
                float m2 = M02 * xv0 + M12 * xv1 + M22 * xv2;

#pragma unroll
                for (int t = 0; t < 5; ++t) {
                    half8 w;
#pragma unroll
                    for (int z = 0; z < 8; ++z)
                        w[z] = A[t][z] + (B[t][z] - A[t][z]) * th;   // fp16 lerp
                    if (t == 0) {
#pragma unroll
                        for (int z = 0; z < 8; ++z) V[z] = fmaf(xu, (float)w[z], V[z]);
                    } else if (t == 1) {
#pragma unroll
                        for (int z = 0; z < 8; ++z) V[z] = fmaf(qu, (float)w[z], V[z]);
                    } else if (t == 2) {
#pragma unroll
                        for (int z = 0; z < 8; ++z) {
                            float cw = xu * (float)w[z];
                            V[8 + 3 * z]  = fmaf(cw, nx, V[8 + 3 * z]);
                            V[9 + 3 * z]  = fmaf(cw, ny, V[9 + 3 * z]);
                            V[10 + 3 * z] = fmaf(cw, nz, V[10 + 3 * z]);
                        }
                    } else if (t == 3) {
#pragma unroll
                        for (int z = 0; z < 8; ++z) {
                            float wd = (float)w[z] * INV_S3;
                            V[8 + 3 * z]  = fmaf(xv0, wd, V[8 + 3 * z]);
                            V[9 + 3 * z]  = fmaf(xv1, wd, V[9 + 3 * z]);
                            V[10 + 3 * z] = fmaf(xv2, wd, V[10 + 3 * z]);
                        }
                    } else {
#pragma unroll
                        for (int z = 0; z < 8; ++z) {
                            float we = (float)w[z];
                            V[8 + 3 * z]  = fmaf(m0, we, V[8 + 3 * z]);
                            V[9 + 3 * z]  = fmaf(m1, we, V[9 + 3 * z]);
                            V[10 + 3 * z] = fmaf(m2, we, V[10 + 3 * z]);
                        }
                    }
                }
            }
        }

        // recursive-halving reduce-scatter; lane ends with channel lane&31
#pragma unroll
        for (int h = 16; h >= 1; h >>= 1) {
            bool hi = (lane & h) != 0;
#pragma unroll
            for (int k = 0; k < h; ++k) {
                float lo = V[k], up = V[k + h];
                float keep = hi ? up : lo;
                float send = hi ? lo : up;
                V[k] = keep + __shfl_xor(send, h, 64);
            }
        }
        V[0] += __shfl_xor(V[0], 32, 64);

        if (lane < 32) {
            float v = V[0] * 0.125f * (lane < 8 ? A0S : A1S);
            if (lane < 8) v = v / (1.0f + __expf(-v));   // silu
            y[(size_t)n * 32 + lane] = v;
        }
    }
}

// ---------------------------------------------------------------------------
extern "C" void kernel_launch(void* const* d_in, const int* in_sizes, int n_in,
                              void* d_out, int out_size, void* d_ws, size_t ws_size,
                              hipStream_t stream) {
    const float* x   = (const float*)d_in[0];
    const float* pos = (const float*)d_in[1];
    const int*   ei  = (const int*)d_in[2];
    const float* W1  = (const float*)d_in[3];
    const float* W2  = (const float*)d_in[4];
    int N = in_sizes[1] / 3;
    int E = in_sizes[2] / 2;

    char* ws = (char*)d_ws;
    size_t off = 0;
    _Float16* T    = (_Float16*)(ws + off); off += (size_t)TBL * 320 * 2;   // 1.31 MB
    int*      cnt  = (int*)(ws + off);      off += (size_t)N * 4;           // 100 KB
    int*      ticket = (int*)(ws + off);    off += 64;                      // with cnt memset
    int*      scol = (int*)(ws + off);      off += (size_t)N * CAP * 4;     // 12.8 MB

    float* y = (float*)d_out;

    hipMemsetAsync(cnt, 0, (size_t)N * 4 + 64, stream);   // cnt + ticket
    hipLaunchKernelGGL(prep_all, dim3(TBL / 8), dim3(320), 0, stream,
                       W1, W2, ei, T, cnt, scol, E);
    hipLaunchKernelGGL(tfn_node, dim3(2048), dim3(256), 0, stream,
                       x, pos, scol, cnt, T, ticket, y, N);
}

// Round 8
// 168.940 us; speedup vs baseline: 2.9391x; 2.9391x over previous
//
#include <hip/hip_runtime.h>
#include <hip/hip_fp16.h>

// ---------------------------------------------------------------------------
// TFN-lite layer, MI355X, round 8. Three graph nodes:
//   memset(cnt) -> prep_all(LDS fold + table + scatter) -> tfn_node.
//
//  * wa(d) fp16 table T[j][c'], c' = t*64 + (u*8+wo); 8-lane edge-groups read
//    each 128B chunk coalesced (proven R4/R6 layout).
//  * prep_all (R7): per block, fold W2 -> w2s[64][320] fp32 in LDS (80 KB),
//    then 8 table rows computed from LDS (R6 did 576 divergent L2 loads/wave).
//  * Bucket CSR: scol[row*CAP + atomicAdd(cnt[row])]; CAP=128 >> Poisson(16).
//  * tfn_node (R6, proven): STATIC one wave per node (NO ticket -- R7's
//    single-cacheline ticket atomics serialized the whole grid, 60->383us),
//    recursive-halving reduce-scatter, lane<32 coalesced store + fused silu.
//    New vs R6: packed half8 lerp (v_pk_fma_f16) instead of scalarized loop.
// ---------------------------------------------------------------------------

#define INV_S3  0.5773502691896258f   // 1/sqrt(3)
#define A0S     0.1767766952966369f   // 1/sqrt(32)
#define A1S     0.27386127875258306f  // sqrt(3)/sqrt(40)
#define S15     3.872983346207417f    // sqrt(15)
#define S5      2.23606797749979f     // sqrt(5)
#define INV_S10 0.31622776601683794f  // 1/sqrt(10)   (cg121 normalized)
#define INV_S30 0.18257418583505536f  // 1/sqrt(30)

#define TBL   2048
#define DMAX  8.0f
#define CAP   128

typedef _Float16 half8 __attribute__((ext_vector_type(8)));

// ---------------------------------------------------------------------------
// K1: fold W2 into LDS once per block, build 8 table rows from LDS, then
// grid-stride bucket scatter of edges.
__global__ __launch_bounds__(320) void prep_all(
    const float* __restrict__ W1, const float* __restrict__ W2,
    const int* __restrict__ ei, _Float16* __restrict__ T,
    int* __restrict__ cnt, int* __restrict__ scol, int E) {

    __shared__ float w2s[64 * 320];   // 80 KiB folded weights
    __shared__ float hs[64];
    int tid = threadIdx.x;            // 0..319  == table column c'
    int bid = blockIdx.x;

    // ---- fold: w2s[k][c'] = folded W2 column (L2-hot) ----
    {
        int t = tid >> 6, r = tid & 63;
        int u = r >> 3, wo = r & 7;
        int src = (t < 4) ? (t * 128 + u * 16 + wo) : (512 + u * 8 + wo);
        bool twin = (t < 4);
        for (int k = 0; k < 64; ++k) {
            float v = W2[k * 576 + src];
            if (twin) v += W2[k * 576 + src + 8];
            w2s[k * 320 + tid] = v;
        }
    }

    // ---- 8 table rows for this block ----
    for (int jj = 0; jj < 8; ++jj) {
        int j = bid * 8 + jj;
        float d = (float)j * (DMAX / (float)(TBL - 1));
        __syncthreads();              // fold / hs-rewrite protection
        if (tid < 64) {
            float acc = 0.f;
#pragma unroll
            for (int i = 0; i < 16; ++i) {
                float t = d - (float)i * (1.0f / 3.0f);
                float r = __expf(-4.5f * t * t);
                acc = fmaf(r, W1[i * 64 + tid], acc);
            }
            hs[tid] = fmaxf(acc, 0.f) * 0.25f;   // /sqrt(16)
        }
        __syncthreads();
        float acc = 0.f;
#pragma unroll 8
        for (int k = 0; k < 64; ++k) acc = fmaf(hs[k], w2s[k * 320 + tid], acc);
        T[(size_t)j * 320 + tid] = (_Float16)acc;
    }

    // ---- bucket scatter (independent of table phase) ----
    int gtid = bid * 320 + tid;
    int gsz = gridDim.x * 320;
    for (int e = gtid; e < E; e += gsz) {
        int row = ei[e];
        int p = atomicAdd(&cnt[row], 1);
        if (p < CAP) scol[(size_t)row * CAP + p] = ei[E + e];
    }
}

// ---------------------------------------------------------------------------
// K2: one wave per node (static), 4 waves per block.
__global__ __launch_bounds__(256) void tfn_node(
    const float* __restrict__ x, const float* __restrict__ pos,
    const int* __restrict__ scol, const int* __restrict__ cnt,
    const _Float16* __restrict__ T, float* __restrict__ y, int N) {

    int wv = threadIdx.x >> 6, lane = threadIdx.x & 63;
    int n = blockIdx.x * 4 + wv;
    if (n >= N) return;                 // wave-uniform

    int g = lane >> 3;
    int u = lane & 7;
    int kc = cnt[n];
    if (kc > CAP) kc = CAP;
    const int* nbr = scol + (size_t)n * CAP;

    const float* xr = x + (size_t)n * 32;
    float xu  = xr[u];
    float xv0 = xr[8 + 3 * u + 0];
    float xv1 = xr[8 + 3 * u + 1];
    float xv2 = xr[8 + 3 * u + 2];
    float prx = pos[3 * n + 0], pry = pos[3 * n + 1], prz = pos[3 * n + 2];

    // V: 32 output channels (final layout). V[z]=scalar z; vec w comp k -> V[8+3w+k].
    float V[32];
#pragma unroll
    for (int z = 0; z < 32; ++z) V[z] = 0.f;

    int rounds = (kc + 7) >> 3;
    for (int rd = 0; rd < rounds; ++rd) {
        int slot = rd * 8 + g;
        if (slot < kc) {
            int col = nbr[slot];
            float evx = prx - pos[3 * col + 0];
            float evy = pry - pos[3 * col + 1];
            float evz = prz - pos[3 * col + 2];
            float d2 = evx * evx + evy * evy + evz * evz + 1e-12f;
            float invd = rsqrtf(d2);
            float dd = d2 * invd;
            float nx = evx * invd, ny = evy * invd, nz = evz * invd;

            float fj = dd * ((float)(TBL - 1) / DMAX);
            int j0 = (int)fj;
            j0 = min(j0, TBL - 2);
            float tf = fminf(fj - (float)j0, 1.0f);
            _Float16 th = (_Float16)tf;

            const _Float16* Ar = T + (size_t)j0 * 320 + u * 8;
            half8 A[5], B[5];
#pragma unroll
            for (int t = 0; t < 5; ++t) {
                A[t] = *(const half8*)(Ar + t * 64);
                B[t] = *(const half8*)(Ar + 320 + t * 64);
            }

            float qu = xv0 * nx + xv1 * ny + xv2 * nz;   // (xv[u].Y1)/S3
            float Y22 = 0.5f * S5 * (3.f * ny * ny - 1.f);
            float Y24 = 0.5f * S15 * (nz * nz - nx * nx);
            float M00 = -Y22 * INV_S30 - Y24 * INV_S10;
            float M11 = 2.f * Y22 * INV_S30;
            float M22 = -Y22 * INV_S30 + Y24 * INV_S10;
            float M01 = (S15 * nx * ny) * INV_S10;
            float M02 = (S15 * nx * nz) * INV_S10;
            float M12 = (S15 * ny * nz) * INV_S10;
            float m0 = M00 * xv0 + M01 * xv1 + M02 * xv2;
            float m1 = M01 * xv0 + M11 * xv1 + M12 * xv2;
            float m2 = M02 * xv0 + M12 * xv1 + M22 * xv2;

#pragma unroll
            for (int t = 0; t < 5; ++t) {
                half8 w = A[t] + (B[t] - A[t]) * th;   // packed v_pk_fma_f16
                if (t == 0) {
#pragma unroll
                    for (int z = 0; z < 8; ++z) V[z] = fmaf(xu, (float)w[z], V[z]);
                } else if (t == 1) {
#pragma unroll
                    for (int z = 0; z < 8; ++z) V[z] = fmaf(qu, (float)w[z], V[z]);
                } else if (t == 2) {
#pragma unroll
                    for (int z = 0; z < 8; ++z) {
                        float cw = xu * (float)w[z];
                        V[8 + 3 * z]  = fmaf(cw, nx, V[8 + 3 * z]);
                        V[9 + 3 * z]  = fmaf(cw, ny, V[9 + 3 * z]);
                        V[10 + 3 * z] = fmaf(cw, nz, V[10 + 3 * z]);
                    }
                } else if (t == 3) {
#pragma unroll
                    for (int z = 0; z < 8; ++z) {
                        float wd = (float)w[z] * INV_S3;
                        V[8 + 3 * z]  = fmaf(xv0, wd, V[8 + 3 * z]);
                        V[9 + 3 * z]  = fmaf(xv1, wd, V[9 + 3 * z]);
                        V[10 + 3 * z] = fmaf(xv2, wd, V[10 + 3 * z]);
                    }
                } else {
#pragma unroll
                    for (int z = 0; z < 8; ++z) {
                        float we = (float)w[z];
                        V[8 + 3 * z]  = fmaf(m0, we, V[8 + 3 * z]);
                        V[9 + 3 * z]  = fmaf(m1, we, V[9 + 3 * z]);
                        V[10 + 3 * z] = fmaf(m2, we, V[10 + 3 * z]);
                    }
                }
            }
        }
    }

    // recursive-halving reduce-scatter; lane ends with channel lane&31 in V[0]
#pragma unroll
    for (int h = 16; h >= 1; h >>= 1) {
        bool hi = (lane & h) != 0;
#pragma unroll
        for (int k = 0; k < h; ++k) {
            float lo = V[k], up = V[k + h];
            float keep = hi ? up : lo;
            float send = hi ? lo : up;
            V[k] = keep + __shfl_xor(send, h, 64);
        }
    }
    V[0] += __shfl_xor(V[0], 32, 64);

    if (lane < 32) {
        float v = V[0] * 0.125f * (lane < 8 ? A0S : A1S);
        if (lane < 8) v = v / (1.0f + __expf(-v));   // silu
        y[(size_t)n * 32 + lane] = v;
    }
}

// ---------------------------------------------------------------------------
extern "C" void kernel_launch(void* const* d_in, const int* in_sizes, int n_in,
                              void* d_out, int out_size, void* d_ws, size_t ws_size,
                              hipStream_t stream) {
    const float* x   = (const float*)d_in[0];
    const float* pos = (const float*)d_in[1];
    const int*   ei  = (const int*)d_in[2];
    const float* W1  = (const float*)d_in[3];
    const float* W2  = (const float*)d_in[4];
    int N = in_sizes[1] / 3;
    int E = in_sizes[2] / 2;

    char* ws = (char*)d_ws;
    size_t off = 0;
    _Float16* T    = (_Float16*)(ws + off); off += (size_t)TBL * 320 * 2;   // 1.31 MB
    int*      cnt  = (int*)(ws + off);      off += (size_t)N * 4;           // 100 KB
    int*      scol = (int*)(ws + off);      off += (size_t)N * CAP * 4;     // 12.8 MB

    float* y = (float*)d_out;

    hipMemsetAsync(cnt, 0, (size_t)N * 4, stream);
    hipLaunchKernelGGL(prep_all, dim3(TBL / 8), dim3(320), 0, stream,
                       W1, W2, ei, T, cnt, scol, E);
    hipLaunchKernelGGL(tfn_node, dim3((N + 3) / 4), dim3(256), 0, stream,
                       x, pos, scol, cnt, T, y, N);
}

// Round 9
// 154.942 us; speedup vs baseline: 3.2047x; 1.0903x over previous
//
#include <hip/hip_runtime.h>
#include <hip/hip_fp16.h>

// ---------------------------------------------------------------------------
// TFN-lite layer, MI355X, round 9. Five graph nodes:
//   memset(cnt) -> fold_w2 -> build_table -> scatter -> tfn_node.
//
//  * R8's prep_all (80KB-LDS monolith) ran at 1 block/CU, 5 waves/CU ->
//    62us of exposed latency (VALUBusy 3.8%). Split into three small
//    high-occupancy kernels; no phase carries big LDS.
//  * W2f[64][320] folded once to global; table kernel reads it COALESCED
//    (R6's mistake was divergent inline folding; R8's was LDS occupancy).
//  * wa(d) fp16 table T[j][c'], c' = t*64 + (u*8+wo); 8-lane edge-groups
//    read each 128B chunk coalesced (proven layout).
//  * Bucket CSR: scol[row*CAP + atomicAdd(cnt[row])]; CAP=128 >> Poisson(16).
//  * tfn_node: UNCHANGED from R8 (proven 60us): static wave/node, packed
//    half8 lerp, recursive-halving reduce-scatter, fused silu store.
// ---------------------------------------------------------------------------

#define INV_S3  0.5773502691896258f   // 1/sqrt(3)
#define A0S     0.1767766952966369f   // 1/sqrt(32)
#define A1S     0.27386127875258306f  // sqrt(3)/sqrt(40)
#define S15     3.872983346207417f    // sqrt(15)
#define S5      2.23606797749979f     // sqrt(5)
#define INV_S10 0.31622776601683794f  // 1/sqrt(10)   (cg121 normalized)
#define INV_S30 0.18257418583505536f  // 1/sqrt(30)

#define TBL   2048
#define DMAX  8.0f
#define CAP   128

typedef _Float16 half8 __attribute__((ext_vector_type(8)));

// ---------------------------------------------------------------------------
// K1: fold W2 (64x576) -> W2f[k*320 + c'], c' = t*64 + u*8 + wo.
__global__ __launch_bounds__(256) void fold_w2(
    const float* __restrict__ W2, float* __restrict__ W2f) {
    int idx = blockIdx.x * 256 + threadIdx.x;
    if (idx >= 64 * 320) return;
    int k = idx / 320;
    int c = idx - k * 320;
    int t = c >> 6, r = c & 63;
    int u = r >> 3, wo = r & 7;
    const float* Wk = W2 + k * 576;
    float v;
    if (t < 4) {
        int base = t * 128 + u * 16 + wo;
        v = Wk[base] + Wk[base + 8];
    } else {
        v = Wk[512 + u * 8 + wo];
    }
    W2f[k * 320 + c] = v;
}

// ---------------------------------------------------------------------------
// K2: one block per table row j; 320 threads = columns; W2f rows coalesced.
__global__ __launch_bounds__(320) void build_table(
    const float* __restrict__ W1, const float* __restrict__ W2f,
    _Float16* __restrict__ T) {
    __shared__ float hs[64];
    int j = blockIdx.x;
    int tid = threadIdx.x;
    float d = (float)j * (DMAX / (float)(TBL - 1));
    if (tid < 64) {
        float acc = 0.f;
#pragma unroll
        for (int i = 0; i < 16; ++i) {
            float t = d - (float)i * (1.0f / 3.0f);
            float r = __expf(-4.5f * t * t);
            acc = fmaf(r, W1[i * 64 + tid], acc);
        }
        hs[tid] = fmaxf(acc, 0.f) * 0.25f;   // /sqrt(16)
    }
    __syncthreads();
    float acc = 0.f;
#pragma unroll 8
    for (int k = 0; k < 64; ++k) acc = fmaf(hs[k], W2f[k * 320 + tid], acc);
    T[(size_t)j * 320 + tid] = (_Float16)acc;
}

// ---------------------------------------------------------------------------
// K3: bucket scatter, one edge per thread, full occupancy.
__global__ __launch_bounds__(256) void scatter(
    const int* __restrict__ ei, int* __restrict__ cnt,
    int* __restrict__ scol, int E) {
    int e = blockIdx.x * 256 + threadIdx.x;
    if (e >= E) return;
    int row = ei[e];
    int p = atomicAdd(&cnt[row], 1);
    if (p < CAP) scol[(size_t)row * CAP + p] = ei[E + e];
}

// ---------------------------------------------------------------------------
// K4: one wave per node (static), 4 waves per block. (R8, unchanged.)
__global__ __launch_bounds__(256) void tfn_node(
    const float* __restrict__ x, const float* __restrict__ pos,
    const int* __restrict__ scol, const int* __restrict__ cnt,
    const _Float16* __restrict__ T, float* __restrict__ y, int N) {

    int wv = threadIdx.x >> 6, lane = threadIdx.x & 63;
    int n = blockIdx.x * 4 + wv;
    if (n >= N) return;                 // wave-uniform

    int g = lane >> 3;
    int u = lane & 7;
    int kc = cnt[n];
    if (kc > CAP) kc = CAP;
    const int* nbr = scol + (size_t)n * CAP;

    const float* xr = x + (size_t)n * 32;
    float xu  = xr[u];
    float xv0 = xr[8 + 3 * u + 0];
    float xv1 = xr[8 + 3 * u + 1];
    float xv2 = xr[8 + 3 * u + 2];
    float prx = pos[3 * n + 0], pry = pos[3 * n + 1], prz = pos[3 * n + 2];

    // V: 32 output channels (final layout). V[z]=scalar z; vec w comp k -> V[8+3w+k].
    float V[32];
#pragma unroll
    for (int z = 0; z < 32; ++z) V[z] = 0.f;

    int rounds = (kc + 7) >> 3;
    for (int rd = 0; rd < rounds; ++rd) {
        int slot = rd * 8 + g;
        if (slot < kc) {
            int col = nbr[slot];
            float evx = prx - pos[3 * col + 0];
            float evy = pry - pos[3 * col + 1];
            float evz = prz - pos[3 * col + 2];
            float d2 = evx * evx + evy * evy + evz * evz + 1e-12f;
            float invd = rsqrtf(d2);
            float dd = d2 * invd;
            float nx = evx * invd, ny = evy * invd, nz = evz * invd;

            float fj = dd * ((float)(TBL - 1) / DMAX);
            int j0 = (int)fj;
            j0 = min(j0, TBL - 2);
            float tf = fminf(fj - (float)j0, 1.0f);
            _Float16 th = (_Float16)tf;

            const _Float16* Ar = T + (size_t)j0 * 320 + u * 8;
            half8 A[5], B[5];
#pragma unroll
            for (int t = 0; t < 5; ++t) {
                A[t] = *(const half8*)(Ar + t * 64);
                B[t] = *(const half8*)(Ar + 320 + t * 64);
            }

            float qu = xv0 * nx + xv1 * ny + xv2 * nz;   // (xv[u].Y1)/S3
            float Y22 = 0.5f * S5 * (3.f * ny * ny - 1.f);
            float Y24 = 0.5f * S15 * (nz * nz - nx * nx);
            float M00 = -Y22 * INV_S30 - Y24 * INV_S10;
            float M11 = 2.f * Y22 * INV_S30;
            float M22 = -Y22 * INV_S30 + Y24 * INV_S10;
            float M01 = (S15 * nx * ny) * INV_S10;
            float M02 = (S15 * nx * nz) * INV_S10;
            float M12 = (S15 * ny * nz) * INV_S10;
            float m0 = M00 * xv0 + M01 * xv1 + M02 * xv2;
            float m1 = M01 * xv0 + M11 * xv1 + M12 * xv2;
            float m2 = M02 * xv0 + M12 * xv1 + M22 * xv2;

#pragma unroll
            for (int t = 0; t < 5; ++t) {
                half8 w = A[t] + (B[t] - A[t]) * th;   // packed v_pk_fma_f16
                if (t == 0) {
#pragma unroll
                    for (int z = 0; z < 8; ++z) V[z] = fmaf(xu, (float)w[z], V[z]);
                } else if (t == 1) {
#pragma unroll
                    for (int z = 0; z < 8; ++z) V[z] = fmaf(qu, (float)w[z], V[z]);
                } else if (t == 2) {
#pragma unroll
                    for (int z = 0; z < 8; ++z) {
                        float cw = xu * (float)w[z];
                        V[8 + 3 * z]  = fmaf(cw, nx, V[8 + 3 * z]);
                        V[9 + 3 * z]  = fmaf(cw, ny, V[9 + 3 * z]);
                        V[10 + 3 * z] = fmaf(cw, nz, V[10 + 3 * z]);
                    }
                } else if (t == 3) {
#pragma unroll
                    for (int z = 0; z < 8; ++z) {
                        float wd = (float)w[z] * INV_S3;
                        V[8 + 3 * z]  = fmaf(xv0, wd, V[8 + 3 * z]);
                        V[9 + 3 * z]  = fmaf(xv1, wd, V[9 + 3 * z]);
                        V[10 + 3 * z] = fmaf(xv2, wd, V[10 + 3 * z]);
                    }
                } else {
#pragma unroll
                    for (int z = 0; z < 8; ++z) {
                        float we = (float)w[z];
                        V[8 + 3 * z]  = fmaf(m0, we, V[8 + 3 * z]);
                        V[9 + 3 * z]  = fmaf(m1, we, V[9 + 3 * z]);
                        V[10 + 3 * z] = fmaf(m2, we, V[10 + 3 * z]);
                    }
                }
            }
        }
    }

    // recursive-halving reduce-scatter; lane ends with channel lane&31 in V[0]
#pragma unroll
    for (int h = 16; h >= 1; h >>= 1) {
        bool hi = (lane & h) != 0;
#pragma unroll
        for (int k = 0; k < h; ++k) {
            float lo = V[k], up = V[k + h];
            float keep = hi ? up : lo;
            float send = hi ? lo : up;
            V[k] = keep + __shfl_xor(send, h, 64);
        }
    }
    V[0] += __shfl_xor(V[0], 32, 64);

    if (lane < 32) {
        float v = V[0] * 0.125f * (lane < 8 ? A0S : A1S);
        if (lane < 8) v = v / (1.0f + __expf(-v));   // silu
        y[(size_t)n * 32 + lane] = v;
    }
}

// ---------------------------------------------------------------------------
extern "C" void kernel_launch(void* const* d_in, const int* in_sizes, int n_in,
                              void* d_out, int out_size, void* d_ws, size_t ws_size,
                              hipStream_t stream) {
    const float* x   = (const float*)d_in[0];
    const float* pos = (const float*)d_in[1];
    const int*   ei  = (const int*)d_in[2];
    const float* W1  = (const float*)d_in[3];
    const float* W2  = (const float*)d_in[4];
    int N = in_sizes[1] / 3;
    int E = in_sizes[2] / 2;

    char* ws = (char*)d_ws;
    size_t off = 0;
    _Float16* T    = (_Float16*)(ws + off); off += (size_t)TBL * 320 * 2;   // 1.31 MB
    float*    W2f  = (float*)(ws + off);    off += (size_t)64 * 320 * 4;    // 80 KB
    int*      cnt  = (int*)(ws + off);      off += (size_t)N * 4;           // 100 KB
    int*      scol = (int*)(ws + off);      off += (size_t)N * CAP * 4;     // 12.8 MB

    float* y = (float*)d_out;

    hipMemsetAsync(cnt, 0, (size_t)N * 4, stream);
    hipLaunchKernelGGL(fold_w2, dim3((64 * 320 + 255) / 256), dim3(256), 0, stream, W2, W2f);
    hipLaunchKernelGGL(build_table, dim3(TBL), dim3(320), 0, stream, W1, W2f, T);
    hipLaunchKernelGGL(scatter, dim3((E + 255) / 256), dim3(256), 0, stream, ei, cnt, scol, E);
    hipLaunchKernelGGL(tfn_node, dim3((N + 3) / 4), dim3(256), 0, stream,
                       x, pos, scol, cnt, T, y, N);
}